// Round 1
// baseline (3210.206 us; speedup 1.0000x reference)
//
#include <hip/hip_runtime.h>
#include <math.h>

// BinaryTreeLSTM on MI355X — round 1: correct fp32 baseline.
//
// Reference structure (DEPTH=12, H=I=1024, N=4095 nodes):
//   for k = 11..0: n = 2^k
//     gates(n,8192) = emb[n-1:2n-1] @ W_ih.T + h.reshape(n,2048) @ W_hh.T + b
//     i,f,g,o = split(gates); c_new = sig(f)*c_cat + sig(i)*tanh(g)
//     h_new = sig(o)*tanh(c_new); h = h_new[:, :1024]; c = c_new[:, :1024]
//   out = concat([h, c], axis=1)  -> 2048 floats
//
// Exploited structure:
//  * only gate columns j < 1024 survive -> effective W rows r = g*2048 + j
//    (4096 rows, not 8192): halves all GEMM work.
//  * level 11 has h = c = 0 -> skip the W_hh GEMM entirely there.

#define HDIM 1024
#define TREE_DEPTH 12
#define GCOLS 4096   // effective gate columns (4 gates x 1024)

// ---------------------------------------------------------------- bias prep
__global__ void bias_kernel(const float* __restrict__ b_ih,
                            const float* __restrict__ b_hh,
                            float* __restrict__ bg) {
    int idx = blockIdx.x * blockDim.x + threadIdx.x;   // 0..4095
    int g = idx >> 10, j = idx & 1023;
    int r = g * 2048 + j;
    bg[idx] = b_ih[r] + b_hh[r];
}

// ---------------------------------------------------------------- level GEMM
// gates[m][c] = sum_k x[m][k]*W_ih[row(c)][k]            (k in [0,1024))
//             + sum_k hprev[m][k]*W_hh[row(c)][k]        (k in [0,2048), if has_h)
//             + bg[c]
// row(c) = (c>>10)*2048 + (c&1023)
// Tile 64x64, K-step 16, 256 threads, 4x4 micro-tile per thread.
__global__ __launch_bounds__(256) void level_gemm(
    const float* __restrict__ x,       // n x 1024   (= emb + (n-1)*1024)
    const float* __restrict__ hprev,   // n x 2048 flat (or nullptr)
    const float* __restrict__ W_ih,    // 8192 x 1024
    const float* __restrict__ W_hh,    // 8192 x 2048
    const float* __restrict__ bg,      // 4096
    float* __restrict__ gates,         // n x 4096
    int n, int has_h)
{
    __shared__ float As[16][64];
    __shared__ float Bs[16][64];

    const int tid = threadIdx.x;
    const int tx = tid & 15;          // col group for compute
    const int ty = tid >> 4;          // row group for compute
    const int m_base = blockIdx.x * 64;
    const int c_base = blockIdx.y * 64;

    // load mapping: one float4 per thread per tile
    const int ldr = tid >> 2;         // 0..63 (row of A-tile / col of B-tile)
    const int k4  = (tid & 3) * 4;    // 0,4,8,12

    const int cg   = c_base + ldr;                    // global gate col for B load
    const int wrow = (cg >> 10) * 2048 + (cg & 1023); // W row index
    const int mg_l = m_base + ldr;                    // global node row for A load

    float acc[4][4] = {};
    const int Ktot = has_h ? 3072 : 1024;

    for (int k0 = 0; k0 < Ktot; k0 += 16) {
        const int k = k0 + k4;
        float4 av = make_float4(0.f, 0.f, 0.f, 0.f);
        if (mg_l < n) {
            if (k < 1024)
                av = *reinterpret_cast<const float4*>(x + (size_t)mg_l * 1024 + k);
            else
                av = *reinterpret_cast<const float4*>(hprev + (size_t)mg_l * 2048 + (k - 1024));
        }
        float4 bv;
        if (k < 1024)
            bv = *reinterpret_cast<const float4*>(W_ih + (size_t)wrow * 1024 + k);
        else
            bv = *reinterpret_cast<const float4*>(W_hh + (size_t)wrow * 2048 + (k - 1024));

        __syncthreads();
        As[k4 + 0][ldr] = av.x; As[k4 + 1][ldr] = av.y;
        As[k4 + 2][ldr] = av.z; As[k4 + 3][ldr] = av.w;
        Bs[k4 + 0][ldr] = bv.x; Bs[k4 + 1][ldr] = bv.y;
        Bs[k4 + 2][ldr] = bv.z; Bs[k4 + 3][ldr] = bv.w;
        __syncthreads();

        #pragma unroll
        for (int kk = 0; kk < 16; ++kk) {
            float a[4], b[4];
            #pragma unroll
            for (int i = 0; i < 4; ++i) a[i] = As[kk][ty * 4 + i];
            #pragma unroll
            for (int j = 0; j < 4; ++j) b[j] = Bs[kk][tx * 4 + j];
            #pragma unroll
            for (int i = 0; i < 4; ++i)
                #pragma unroll
                for (int j = 0; j < 4; ++j)
                    acc[i][j] += a[i] * b[j];
        }
    }

    #pragma unroll
    for (int i = 0; i < 4; ++i) {
        const int mg = m_base + ty * 4 + i;
        if (mg < n) {
            #pragma unroll
            for (int j = 0; j < 4; ++j) {
                const int cgj = c_base + tx * 4 + j;
                gates[(size_t)mg * GCOLS + cgj] = acc[i][j] + bg[cgj];
            }
        }
    }
}

// ---------------------------------------------------------------- LSTM cell
__global__ void level_act(const float* __restrict__ gates,  // n x 4096
                          const float* __restrict__ cprev,  // n x 2048 flat (or nullptr)
                          float* __restrict__ hnext,        // n x 1024
                          float* __restrict__ cnext,        // n x 1024
                          int n, int has_h)
{
    int idx = blockIdx.x * blockDim.x + threadIdx.x;
    if (idx >= n * HDIM) return;
    int m = idx >> 10, j = idx & 1023;
    const float* gr = gates + (size_t)m * GCOLS;
    float iv = gr[j];
    float fv = gr[1024 + j];
    float gv = gr[2048 + j];
    float ov = gr[3072 + j];
    float cc = has_h ? cprev[(size_t)m * 2048 + j] : 0.0f;
    float si = 1.0f / (1.0f + expf(-iv));
    float sf = 1.0f / (1.0f + expf(-fv));
    float so = 1.0f / (1.0f + expf(-ov));
    float cn = sf * cc + si * tanhf(gv);
    float hn = so * tanhf(cn);
    hnext[(size_t)m * HDIM + j] = hn;
    cnext[(size_t)m * HDIM + j] = cn;
}

// ---------------------------------------------------------------- launcher
extern "C" void kernel_launch(void* const* d_in, const int* in_sizes, int n_in,
                              void* d_out, int out_size, void* d_ws, size_t ws_size,
                              hipStream_t stream) {
    const float* emb  = (const float*)d_in[0];   // 4095 x 1024
    const float* W_ih = (const float*)d_in[1];   // 8192 x 1024
    const float* W_hh = (const float*)d_in[2];   // 8192 x 2048
    const float* b_ih = (const float*)d_in[3];   // 8192
    const float* b_hh = (const float*)d_in[4];   // 8192
    float* out = (float*)d_out;                  // 2048

    // workspace layout (floats)
    float* bg    = (float*)d_ws;                         // 4096
    float* gates = bg + 4096;                            // 2048*4096 = 8M
    float* hb0   = gates + (size_t)2048 * 4096;          // 2048*1024
    float* cb0   = hb0 + (size_t)2048 * 1024;
    float* hb1   = cb0 + (size_t)2048 * 1024;
    float* cb1   = hb1 + (size_t)2048 * 1024;

    bias_kernel<<<16, 256, 0, stream>>>(b_ih, b_hh, bg);

    const float* hprev = nullptr;
    const float* cprev = nullptr;
    int buf = 0;
    for (int k = TREE_DEPTH - 1; k >= 0; --k) {
        const int n = 1 << k;
        const float* x = emb + (size_t)(n - 1) * 1024;
        const int has_h = (k != TREE_DEPTH - 1);
        float* hn = (k == 0) ? out          : (buf ? hb1 : hb0);
        float* cn = (k == 0) ? (out + 1024) : (buf ? cb1 : cb0);

        dim3 grid((n + 63) / 64, GCOLS / 64);
        level_gemm<<<grid, 256, 0, stream>>>(x, hprev, W_ih, W_hh, bg, gates, n, has_h);

        const int tot = n * HDIM;
        level_act<<<(tot + 255) / 256, 256, 0, stream>>>(gates, cprev, hn, cn, n, has_h);

        hprev = hn; cprev = cn; buf ^= 1;
    }
}

// Round 2
// 659.115 us; speedup vs baseline: 4.8705x; 4.8705x over previous
//
#include <hip/hip_runtime.h>
#include <hip/hip_bf16.h>
#include <math.h>

// BinaryTreeLSTM — round 2: bf16 MFMA with hi/lo split-precision weights.
//
// gates[m][e] (e in [0,4096), e = g*1024+j, W row = g*2048+j) =
//   sum_k A[m][k] * W[e][k],  A = [x | h_cat] (K = 1024 or 3072)
// Weights stored as hi+lo bf16 pairs (error ~2^-18); activations single bf16.

#define HDIM 1024
#define TREE_DEPTH 12
#define GCOLS 4096

typedef unsigned short u16;
typedef unsigned int u32;
typedef __attribute__((ext_vector_type(8))) short bf16x8;
typedef __attribute__((ext_vector_type(4))) float f32x4;

__device__ __forceinline__ void gload16(const void* g, void* l) {
    __builtin_amdgcn_global_load_lds(
        (const __attribute__((address_space(1))) u32*)g,
        (__attribute__((address_space(3))) u32*)l, 16, 0, 0);
}

__device__ __forceinline__ u16 f2bf(float f) {
    __hip_bfloat16 h = __float2bfloat16(f);
    return *reinterpret_cast<u16*>(&h);
}
__device__ __forceinline__ float bf2f(u16 u) {
    __hip_bfloat16 h;
    *reinterpret_cast<u16*>(&h) = u;
    return __bfloat162float(h);
}

// ---------------------------------------------------------------- converts
__global__ void bias_kernel(const float* __restrict__ b_ih,
                            const float* __restrict__ b_hh,
                            float* __restrict__ bg) {
    int idx = blockIdx.x * blockDim.x + threadIdx.x;   // 0..4095
    int g = idx >> 10, j = idx & 1023;
    int r = g * 2048 + j;
    bg[idx] = b_ih[r] + b_hh[r];
}

// W (8192 x K) -> eff (4096 x K) hi/lo bf16.  KSH = log2(K)
template <int KSH>
__global__ void split_w(const float* __restrict__ W,
                        u16* __restrict__ hi, u16* __restrict__ lo) {
    const int K = 1 << KSH;
    size_t idx = ((size_t)blockIdx.x * 256 + threadIdx.x) * 4;  // over 4096*K
    int e = (int)(idx >> KSH);
    int k = (int)(idx & (K - 1));
    int wr = (e >> 10) * 2048 + (e & 1023);
    float4 v = *reinterpret_cast<const float4*>(W + (size_t)wr * K + k);
    u16 h0 = f2bf(v.x), h1 = f2bf(v.y), h2 = f2bf(v.z), h3 = f2bf(v.w);
    u16 l0 = f2bf(v.x - bf2f(h0)), l1 = f2bf(v.y - bf2f(h1));
    u16 l2 = f2bf(v.z - bf2f(h2)), l3 = f2bf(v.w - bf2f(h3));
    uint2 hp = make_uint2((u32)h0 | ((u32)h1 << 16), (u32)h2 | ((u32)h3 << 16));
    uint2 lp = make_uint2((u32)l0 | ((u32)l1 << 16), (u32)l2 | ((u32)l3 << 16));
    *reinterpret_cast<uint2*>(hi + idx) = hp;
    *reinterpret_cast<uint2*>(lo + idx) = lp;
}

__global__ void conv_emb(const float* __restrict__ emb, u16* __restrict__ xb) {
    size_t idx = ((size_t)blockIdx.x * 256 + threadIdx.x) * 4;  // over 4095*1024
    float4 v = *reinterpret_cast<const float4*>(emb + idx);
    uint2 p = make_uint2((u32)f2bf(v.x) | ((u32)f2bf(v.y) << 16),
                         (u32)f2bf(v.z) | ((u32)f2bf(v.w) << 16));
    *reinterpret_cast<uint2*>(xb + idx) = p;
}

// ---------------------------------------------------------------- big GEMM
// n >= 256 (multiple of 128). Tile 128x128, BK=32, 4 waves, 64x64 per wave.
__global__ __launch_bounds__(256) void gemm_big(
    const u16* __restrict__ xb,      // n x 1024
    const u16* __restrict__ hb,      // n x 2048 flat (or null)
    const u16* __restrict__ Wih_hi, const u16* __restrict__ Wih_lo,  // 4096x1024
    const u16* __restrict__ Whh_hi, const u16* __restrict__ Whh_lo,  // 4096x2048
    float* __restrict__ gates,       // n x 4096
    int Ktot)
{
    __shared__ u16 As[128][32];
    __shared__ u16 Bh[128][32];
    __shared__ u16 Bl[128][32];

    const int tid  = threadIdx.x;
    const int lane = tid & 63;
    const int w    = tid >> 6;
    const int wr   = (w >> 1) * 64;
    const int wc   = (w & 1) * 64;
    const int m0   = blockIdx.x * 128;
    const int c0   = blockIdx.y * 128;

    f32x4 acc[4][4];
    #pragma unroll
    for (int i = 0; i < 4; ++i)
        #pragma unroll
        for (int j = 0; j < 4; ++j)
            acc[i][j] = f32x4{0.f, 0.f, 0.f, 0.f};

    const int crow = lane >> 2;        // 0..15 (row within 16-row chunk)
    const int ck   = (lane & 3) * 8;   // elem offset 0,8,16,24

    for (int k0 = 0; k0 < Ktot; k0 += 32) {
        #pragma unroll
        for (int i = 0; i < 2; ++i) {
            const int chunk = w * 2 + i;           // 0..7
            const int r  = chunk * 16 + crow;      // 0..127
            const int kk = k0 + ck;
            const u16* ga = (kk < 1024)
                ? (xb + (size_t)(m0 + r) * 1024 + kk)
                : (hb + (size_t)(m0 + r) * 2048 + (kk - 1024));
            gload16(ga, &As[chunk * 16][0]);
            const int e = c0 + r;
            const u16* gbh = (kk < 1024)
                ? (Wih_hi + (size_t)e * 1024 + kk)
                : (Whh_hi + (size_t)e * 2048 + (kk - 1024));
            const u16* gbl = (kk < 1024)
                ? (Wih_lo + (size_t)e * 1024 + kk)
                : (Whh_lo + (size_t)e * 2048 + (kk - 1024));
            gload16(gbh, &Bh[chunk * 16][0]);
            gload16(gbl, &Bl[chunk * 16][0]);
        }
        __syncthreads();   // drains vmcnt (global_load_lds) + lgkm

        const int fl = lane & 15;
        const int kb = (lane >> 4) * 8;
        bf16x8 a[4], bh[4], bl[4];
        #pragma unroll
        for (int i = 0; i < 4; ++i)
            a[i] = *reinterpret_cast<const bf16x8*>(&As[wr + i * 16 + fl][kb]);
        #pragma unroll
        for (int j = 0; j < 4; ++j) {
            bh[j] = *reinterpret_cast<const bf16x8*>(&Bh[wc + j * 16 + fl][kb]);
            bl[j] = *reinterpret_cast<const bf16x8*>(&Bl[wc + j * 16 + fl][kb]);
        }
        #pragma unroll
        for (int i = 0; i < 4; ++i)
            #pragma unroll
            for (int j = 0; j < 4; ++j) {
                acc[i][j] = __builtin_amdgcn_mfma_f32_16x16x32_bf16(a[i], bh[j], acc[i][j], 0, 0, 0);
                acc[i][j] = __builtin_amdgcn_mfma_f32_16x16x32_bf16(a[i], bl[j], acc[i][j], 0, 0, 0);
            }
        __syncthreads();   // before next stage overwrites LDS
    }

    const int fl = lane & 15;
    const int rg = (lane >> 4) * 4;
    #pragma unroll
    for (int i = 0; i < 4; ++i)
        #pragma unroll
        for (int j = 0; j < 4; ++j) {
            const int c = c0 + wc + j * 16 + fl;
            #pragma unroll
            for (int r = 0; r < 4; ++r) {
                const int m = m0 + wr + i * 16 + rg + r;
                gates[(size_t)m * GCOLS + c] = acc[i][j][r];
            }
        }
}

// ---------------------------------------------------------------- small GEMM
// n <= 128. BM=16, BN=64, K split 8 ways. grid (ceil(n/16), 64, 8).
// Partials: [ks][128][4096] slabs in `partials`.
__global__ __launch_bounds__(256) void gemm_small(
    const u16* __restrict__ xb,      // n x 1024
    const u16* __restrict__ hb,      // n x 2048 flat
    const u16* __restrict__ Wih_hi, const u16* __restrict__ Wih_lo,
    const u16* __restrict__ Whh_hi, const u16* __restrict__ Whh_lo,
    float* __restrict__ partials,
    int n)
{
    __shared__ u16 As[16][32];
    __shared__ u16 Bh[64][32];
    __shared__ u16 Bl[64][32];

    const int tid  = threadIdx.x;
    const int lane = tid & 63;
    const int w    = tid >> 6;
    const int m0   = blockIdx.x * 16;
    const int c0   = blockIdx.y * 64;
    const int ksl  = blockIdx.z;          // 0..7, K chunk of 384

    f32x4 acc = f32x4{0.f, 0.f, 0.f, 0.f};

    const int arow = tid >> 4;            // 0..15
    const int ak   = (tid & 15) * 2;      // 0..30 even
    const int crow = lane >> 2;
    const int ck   = (lane & 3) * 8;

    const int kend = (ksl + 1) * 384;
    for (int k0 = ksl * 384; k0 < kend; k0 += 32) {
        // guarded A load (reg -> LDS)
        u32 av = 0;
        const int m  = m0 + arow;
        const int kk = k0 + ak;
        if (m < n) {
            const u16* pa = (kk < 1024) ? (xb + (size_t)m * 1024 + kk)
                                        : (hb + (size_t)m * 2048 + (kk - 1024));
            av = *reinterpret_cast<const u32*>(pa);
        }
        // B staging: wave w fills its 16-row chunk
        const int e   = c0 + w * 16 + crow;
        const int kb2 = k0 + ck;
        const u16* gbh = (kb2 < 1024) ? (Wih_hi + (size_t)e * 1024 + kb2)
                                      : (Whh_hi + (size_t)e * 2048 + (kb2 - 1024));
        const u16* gbl = (kb2 < 1024) ? (Wih_lo + (size_t)e * 1024 + kb2)
                                      : (Whh_lo + (size_t)e * 2048 + (kb2 - 1024));
        gload16(gbh, &Bh[w * 16][0]);
        gload16(gbl, &Bl[w * 16][0]);
        *reinterpret_cast<u32*>(&As[arow][ak]) = av;
        __syncthreads();

        const int fl = lane & 15;
        const int kb = (lane >> 4) * 8;
        bf16x8 a  = *reinterpret_cast<const bf16x8*>(&As[fl][kb]);
        bf16x8 vh = *reinterpret_cast<const bf16x8*>(&Bh[w * 16 + fl][kb]);
        bf16x8 vl = *reinterpret_cast<const bf16x8*>(&Bl[w * 16 + fl][kb]);
        acc = __builtin_amdgcn_mfma_f32_16x16x32_bf16(a, vh, acc, 0, 0, 0);
        acc = __builtin_amdgcn_mfma_f32_16x16x32_bf16(a, vl, acc, 0, 0, 0);
        __syncthreads();
    }

    const int fl = lane & 15;
    const int rg = (lane >> 4) * 4;
    #pragma unroll
    for (int r = 0; r < 4; ++r) {
        const int m = m0 + rg + r;
        if (m < n)
            partials[((size_t)ksl * 128 + m) * GCOLS + c0 + w * 16 + fl] = acc[r];
    }
}

// ---------------------------------------------------------------- LSTM cell
__global__ void level_act(const float* __restrict__ gsrc, int ks_n, size_t ks_stride,
                          const float* __restrict__ bg,
                          const float* __restrict__ cprev,   // n x 2048 flat
                          u16* __restrict__ hb_next,         // n x 1024 bf16
                          float* __restrict__ cb_next,       // n x 1024 f32
                          float* __restrict__ out,           // null unless n==1
                          int n, int has_h)
{
    int idx = blockIdx.x * blockDim.x + threadIdx.x;
    if (idx >= n * HDIM) return;
    int m = idx >> 10, j = idx & 1023;
    float iv = bg[j], fv = bg[1024 + j], gv = bg[2048 + j], ov = bg[3072 + j];
    for (int s = 0; s < ks_n; ++s) {
        const float* p = gsrc + (size_t)s * ks_stride + (size_t)m * GCOLS;
        iv += p[j]; fv += p[1024 + j]; gv += p[2048 + j]; ov += p[3072 + j];
    }
    float cc = has_h ? cprev[(size_t)m * 2048 + j] : 0.0f;
    float si = 1.0f / (1.0f + expf(-iv));
    float sf = 1.0f / (1.0f + expf(-fv));
    float so = 1.0f / (1.0f + expf(-ov));
    float cn = sf * cc + si * tanhf(gv);
    float hn = so * tanhf(cn);
    hb_next[idx] = f2bf(hn);
    cb_next[idx] = cn;
    if (out) { out[j] = hn; out[1024 + j] = cn; }
}

// ---------------------------------------------------------------- launcher
extern "C" void kernel_launch(void* const* d_in, const int* in_sizes, int n_in,
                              void* d_out, int out_size, void* d_ws, size_t ws_size,
                              hipStream_t stream) {
    const float* emb  = (const float*)d_in[0];
    const float* W_ih = (const float*)d_in[1];
    const float* W_hh = (const float*)d_in[2];
    const float* b_ih = (const float*)d_in[3];
    const float* b_hh = (const float*)d_in[4];
    float* out = (float*)d_out;

    char* p = (char*)d_ws;
    float* bg     = (float*)p;                 p += 16384;
    u16* Wih_hi   = (u16*)p;                   p += (size_t)4096 * 1024 * 2;
    u16* Wih_lo   = (u16*)p;                   p += (size_t)4096 * 1024 * 2;
    u16* Whh_hi   = (u16*)p;                   p += (size_t)4096 * 2048 * 2;
    u16* Whh_lo   = (u16*)p;                   p += (size_t)4096 * 2048 * 2;
    u16* xb       = (u16*)p;                   p += (size_t)4095 * 1024 * 2 + 2048;
    float* gates  = (float*)p;                 p += (size_t)2048 * 4096 * 4;
    u16* hb0      = (u16*)p;                   p += (size_t)2048 * 1024 * 2;
    u16* hb1      = (u16*)p;                   p += (size_t)2048 * 1024 * 2;
    float* cb0    = (float*)p;                 p += (size_t)2048 * 1024 * 4;
    float* cb1    = (float*)p;                 p += (size_t)2048 * 1024 * 4;

    bias_kernel<<<16, 256, 0, stream>>>(b_ih, b_hh, bg);
    split_w<10><<<4096, 256, 0, stream>>>(W_ih, Wih_hi, Wih_lo);
    split_w<11><<<8192, 256, 0, stream>>>(W_hh, Whh_hi, Whh_lo);
    conv_emb<<<4095, 256, 0, stream>>>(emb, xb);

    const u16* hprev = nullptr;
    const float* cprev = nullptr;
    int buf = 0;
    for (int k = TREE_DEPTH - 1; k >= 0; --k) {
        const int n = 1 << k;
        const u16* x = xb + (size_t)(n - 1) * 1024;
        const int has_h = (k != TREE_DEPTH - 1);
        const int Ktot = has_h ? 3072 : 1024;
        u16*   hn = buf ? hb1 : hb0;
        float* cn = buf ? cb1 : cb0;
        float* outp = (k == 0) ? out : nullptr;

        if (n >= 256) {
            dim3 grid(n / 128, GCOLS / 128);
            gemm_big<<<grid, 256, 0, stream>>>(x, hprev, Wih_hi, Wih_lo,
                                               Whh_hi, Whh_lo, gates, Ktot);
            const int tot = n * HDIM;
            level_act<<<(tot + 255) / 256, 256, 0, stream>>>(
                gates, 1, 0, bg, cprev, hn, cn, outp, n, has_h);
        } else {
            dim3 grid((n + 15) / 16, GCOLS / 64, 8);
            gemm_small<<<grid, 256, 0, stream>>>(x, hprev, Wih_hi, Wih_lo,
                                                 Whh_hi, Whh_lo, gates, n);
            const int tot = n * HDIM;
            level_act<<<(tot + 255) / 256, 256, 0, stream>>>(
                gates, 8, (size_t)128 * GCOLS, bg, cprev, hn, cn, outp, n, has_h);
        }
        hprev = hn; cprev = cn; buf ^= 1;
    }
}

// Round 4
// 308.483 us; speedup vs baseline: 10.4064x; 2.1366x over previous
//
#include <hip/hip_runtime.h>
#include <hip/hip_bf16.h>
#include <math.h>

// BinaryTreeLSTM — round 4: round 3 (hi-only bf16 MFMA, K-split, XCD swizzle)
// with the split_w_hi launch grids fixed (4096/8192 blocks, was 1024/2048 —
// which left 3/4 of the converted weights uninitialized).

#define HDIM 1024
#define TREE_DEPTH 12
#define GCOLS 4096

typedef unsigned short u16;
typedef unsigned int u32;
typedef __attribute__((ext_vector_type(8))) short bf16x8;
typedef __attribute__((ext_vector_type(4))) float f32x4;

__device__ __forceinline__ void gload16(const void* g, void* l) {
    __builtin_amdgcn_global_load_lds(
        (const __attribute__((address_space(1))) u32*)g,
        (__attribute__((address_space(3))) u32*)l, 16, 0, 0);
}

__device__ __forceinline__ u16 f2bf(float f) {
    __hip_bfloat16 h = __float2bfloat16(f);
    return *reinterpret_cast<u16*>(&h);
}

// ---------------------------------------------------------------- converts
__global__ void bias_kernel(const float* __restrict__ b_ih,
                            const float* __restrict__ b_hh,
                            float* __restrict__ bg) {
    int idx = blockIdx.x * blockDim.x + threadIdx.x;   // 0..4095
    int g = idx >> 10, j = idx & 1023;
    int r = g * 2048 + j;
    bg[idx] = b_ih[r] + b_hh[r];
}

// W (8192 x K) -> eff (4096 x K) bf16.  KSH = log2(K)
template <int KSH>
__global__ void split_w_hi(const float* __restrict__ W, u16* __restrict__ hi) {
    const int K = 1 << KSH;
    size_t idx = ((size_t)blockIdx.x * 256 + threadIdx.x) * 4;  // over 4096*K
    int e = (int)(idx >> KSH);
    int k = (int)(idx & (K - 1));
    int wr = (e >> 10) * 2048 + (e & 1023);
    float4 v = *reinterpret_cast<const float4*>(W + (size_t)wr * K + k);
    uint2 hp = make_uint2((u32)f2bf(v.x) | ((u32)f2bf(v.y) << 16),
                          (u32)f2bf(v.z) | ((u32)f2bf(v.w) << 16));
    *reinterpret_cast<uint2*>(hi + idx) = hp;
}

__global__ void conv_emb(const float* __restrict__ emb, u16* __restrict__ xb) {
    size_t idx = ((size_t)blockIdx.x * 256 + threadIdx.x) * 4;  // over 4095*1024
    float4 v = *reinterpret_cast<const float4*>(emb + idx);
    uint2 p = make_uint2((u32)f2bf(v.x) | ((u32)f2bf(v.y) << 16),
                         (u32)f2bf(v.z) | ((u32)f2bf(v.w) << 16));
    *reinterpret_cast<uint2*>(xb + idx) = p;
}

// ---------------------------------------------------------------- big GEMM
// n multiple of 128. Tile 128x128, BK=32, 4 waves (64x64 each), K split
// gridDim.z ways into chunks of `kchunk`. Partials slab per K-chunk.
__global__ __launch_bounds__(256) void gemm_big(
    const u16* __restrict__ xb,      // n x 1024
    const u16* __restrict__ hb,      // n x 2048 flat (or null at top level)
    const u16* __restrict__ Wih,     // 4096 x 1024 bf16
    const u16* __restrict__ Whh,     // 4096 x 2048 bf16
    float* __restrict__ partials,    // gridDim.z slabs of n*4096
    int n, int kchunk)
{
    __shared__ u16 As[128][32];
    __shared__ u16 Bs[128][32];

    // XCD-aware bijective swizzle (nwg % 8 == 0 for all configs used),
    // m-tile-fastest: blocks sharing a weight slab (same ct,ks) -> same XCD.
    const int gx = gridDim.x, gy = gridDim.y;
    const int nwg = gx * gy * (int)gridDim.z;
    int id = blockIdx.x + gx * (blockIdx.y + gy * blockIdx.z);
    const int q = nwg >> 3;
    id = (id & 7) * q + (id >> 3);
    const int mt = id % gx;
    const int rest = id / gx;
    const int ct = rest % gy;
    const int ks = rest / gy;

    const int m0 = mt * 128;
    const int c0 = ct * 128;
    const int kbeg = ks * kchunk;
    float* gout = partials + (size_t)ks * n * GCOLS;

    const int tid  = threadIdx.x;
    const int lane = tid & 63;
    const int w    = tid >> 6;
    const int wr   = (w >> 1) * 64;
    const int wc   = (w & 1) * 64;

    f32x4 acc[4][4];
    #pragma unroll
    for (int i = 0; i < 4; ++i)
        #pragma unroll
        for (int j = 0; j < 4; ++j)
            acc[i][j] = f32x4{0.f, 0.f, 0.f, 0.f};

    const int crow = lane >> 2;        // 0..15
    const int ck   = (lane & 3) * 8;   // 0,8,16,24

    for (int k0 = kbeg; k0 < kbeg + kchunk; k0 += 32) {
        #pragma unroll
        for (int i = 0; i < 2; ++i) {
            const int chunk = w * 2 + i;           // 0..7
            const int r  = chunk * 16 + crow;      // 0..127
            const int kk = k0 + ck;
            const u16* ga = (kk < 1024)
                ? (xb + (size_t)(m0 + r) * 1024 + kk)
                : (hb + (size_t)(m0 + r) * 2048 + (kk - 1024));
            gload16(ga, &As[chunk * 16][0]);
            const int e = c0 + r;
            const u16* gb = (kk < 1024)
                ? (Wih + (size_t)e * 1024 + kk)
                : (Whh + (size_t)e * 2048 + (kk - 1024));
            gload16(gb, &Bs[chunk * 16][0]);
        }
        __syncthreads();

        const int fl = lane & 15;
        const int kb = (lane >> 4) * 8;
        bf16x8 a[4], b[4];
        #pragma unroll
        for (int i = 0; i < 4; ++i)
            a[i] = *reinterpret_cast<const bf16x8*>(&As[wr + i * 16 + fl][kb]);
        #pragma unroll
        for (int j = 0; j < 4; ++j)
            b[j] = *reinterpret_cast<const bf16x8*>(&Bs[wc + j * 16 + fl][kb]);
        #pragma unroll
        for (int i = 0; i < 4; ++i)
            #pragma unroll
            for (int j = 0; j < 4; ++j)
                acc[i][j] = __builtin_amdgcn_mfma_f32_16x16x32_bf16(a[i], b[j], acc[i][j], 0, 0, 0);
        __syncthreads();
    }

    const int fl = lane & 15;
    const int rg = (lane >> 4) * 4;
    #pragma unroll
    for (int i = 0; i < 4; ++i)
        #pragma unroll
        for (int j = 0; j < 4; ++j) {
            const int c = c0 + wc + j * 16 + fl;
            #pragma unroll
            for (int r = 0; r < 4; ++r) {
                const int m = m0 + wr + i * 16 + rg + r;
                gout[(size_t)m * GCOLS + c] = acc[i][j][r];
            }
        }
}

// ---------------------------------------------------------------- small GEMM
// n <= 64. BM=16, BN=64, K split 8 ways (chunk 384). grid (ceil(n/16), 64, 8).
__global__ __launch_bounds__(256) void gemm_small(
    const u16* __restrict__ xb,      // n x 1024
    const u16* __restrict__ hb,      // n x 2048 flat
    const u16* __restrict__ Wih, const u16* __restrict__ Whh,
    float* __restrict__ partials,    // 8 slabs of n*4096
    int n)
{
    __shared__ u16 As[16][32];
    __shared__ u16 Bs[64][32];

    const int gx = gridDim.x, gy = gridDim.y;
    const int nwg = gx * gy * 8;
    int id = blockIdx.x + gx * (blockIdx.y + gy * blockIdx.z);
    const int q = nwg >> 3;
    id = (id & 7) * q + (id >> 3);
    const int mt = id % gx;
    const int rest = id / gx;
    const int ct = rest % gy;
    const int ksl = rest / gy;

    const int tid  = threadIdx.x;
    const int lane = tid & 63;
    const int w    = tid >> 6;
    const int m0   = mt * 16;
    const int c0   = ct * 64;

    f32x4 acc = f32x4{0.f, 0.f, 0.f, 0.f};

    const int arow = tid >> 4;            // 0..15
    const int ak   = (tid & 15) * 2;      // 0..30 even
    const int crow = lane >> 2;
    const int ck   = (lane & 3) * 8;

    const int kend = (ksl + 1) * 384;
    for (int k0 = ksl * 384; k0 < kend; k0 += 32) {
        u32 av = 0;
        const int m  = m0 + arow;
        const int kk = k0 + ak;
        if (m < n) {
            const u16* pa = (kk < 1024) ? (xb + (size_t)m * 1024 + kk)
                                        : (hb + (size_t)m * 2048 + (kk - 1024));
            av = *reinterpret_cast<const u32*>(pa);
        }
        const int e   = c0 + w * 16 + crow;
        const int kb2 = k0 + ck;
        const u16* gb = (kb2 < 1024) ? (Wih + (size_t)e * 1024 + kb2)
                                     : (Whh + (size_t)e * 2048 + (kb2 - 1024));
        gload16(gb, &Bs[w * 16][0]);
        *reinterpret_cast<u32*>(&As[arow][ak]) = av;
        __syncthreads();

        const int fl = lane & 15;
        const int kb = (lane >> 4) * 8;
        bf16x8 a = *reinterpret_cast<const bf16x8*>(&As[fl][kb]);
        bf16x8 b = *reinterpret_cast<const bf16x8*>(&Bs[w * 16 + fl][kb]);
        acc = __builtin_amdgcn_mfma_f32_16x16x32_bf16(a, b, acc, 0, 0, 0);
        __syncthreads();
    }

    const int fl = lane & 15;
    const int rg = (lane >> 4) * 4;
    #pragma unroll
    for (int r = 0; r < 4; ++r) {
        const int m = m0 + rg + r;
        if (m < n)
            partials[((size_t)ksl * n + m) * GCOLS + c0 + w * 16 + fl] = acc[r];
    }
}

// ---------------------------------------------------------------- LSTM cell
// Vectorized x4 over j. Sums ks_n partial slabs, adds bias, applies cell.
__global__ void level_act(const float* __restrict__ gsrc, int ks_n, size_t ks_stride,
                          const float* __restrict__ bg,
                          const float* __restrict__ cprev,   // n x 2048 flat
                          u16* __restrict__ hb_next,         // n x 1024 bf16
                          float* __restrict__ cb_next,       // n x 1024 f32
                          float* __restrict__ out,           // null unless n==1
                          int n, int has_h)
{
    int idx = blockIdx.x * blockDim.x + threadIdx.x;   // over n*256
    if (idx >= n * 256) return;
    int m = idx >> 8, j4 = (idx & 255) * 4;

    float4 iv = *reinterpret_cast<const float4*>(bg + j4);
    float4 fv = *reinterpret_cast<const float4*>(bg + 1024 + j4);
    float4 gv = *reinterpret_cast<const float4*>(bg + 2048 + j4);
    float4 ov = *reinterpret_cast<const float4*>(bg + 3072 + j4);
    for (int s = 0; s < ks_n; ++s) {
        const float* p = gsrc + (size_t)s * ks_stride + (size_t)m * GCOLS;
        float4 a = *reinterpret_cast<const float4*>(p + j4);
        float4 b = *reinterpret_cast<const float4*>(p + 1024 + j4);
        float4 c = *reinterpret_cast<const float4*>(p + 2048 + j4);
        float4 d = *reinterpret_cast<const float4*>(p + 3072 + j4);
        iv.x += a.x; iv.y += a.y; iv.z += a.z; iv.w += a.w;
        fv.x += b.x; fv.y += b.y; fv.z += b.z; fv.w += b.w;
        gv.x += c.x; gv.y += c.y; gv.z += c.z; gv.w += c.w;
        ov.x += d.x; ov.y += d.y; ov.z += d.z; ov.w += d.w;
    }
    float4 cc = make_float4(0.f, 0.f, 0.f, 0.f);
    if (has_h) cc = *reinterpret_cast<const float4*>(cprev + (size_t)m * 2048 + j4);

    float cn[4], hn[4];
    float ivv[4] = {iv.x, iv.y, iv.z, iv.w};
    float fvv[4] = {fv.x, fv.y, fv.z, fv.w};
    float gvv[4] = {gv.x, gv.y, gv.z, gv.w};
    float ovv[4] = {ov.x, ov.y, ov.z, ov.w};
    float ccv[4] = {cc.x, cc.y, cc.z, cc.w};
    #pragma unroll
    for (int t = 0; t < 4; ++t) {
        float si = 1.0f / (1.0f + expf(-ivv[t]));
        float sf = 1.0f / (1.0f + expf(-fvv[t]));
        float so = 1.0f / (1.0f + expf(-ovv[t]));
        cn[t] = sf * ccv[t] + si * tanhf(gvv[t]);
        hn[t] = so * tanhf(cn[t]);
    }
    uint2 hp = make_uint2((u32)f2bf(hn[0]) | ((u32)f2bf(hn[1]) << 16),
                          (u32)f2bf(hn[2]) | ((u32)f2bf(hn[3]) << 16));
    *reinterpret_cast<uint2*>(hb_next + (size_t)m * HDIM + j4) = hp;
    *reinterpret_cast<float4*>(cb_next + (size_t)m * HDIM + j4) =
        make_float4(cn[0], cn[1], cn[2], cn[3]);
    if (out) {
        *reinterpret_cast<float4*>(out + j4) = make_float4(hn[0], hn[1], hn[2], hn[3]);
        *reinterpret_cast<float4*>(out + 1024 + j4) = make_float4(cn[0], cn[1], cn[2], cn[3]);
    }
}

// ---------------------------------------------------------------- launcher
extern "C" void kernel_launch(void* const* d_in, const int* in_sizes, int n_in,
                              void* d_out, int out_size, void* d_ws, size_t ws_size,
                              hipStream_t stream) {
    const float* emb  = (const float*)d_in[0];
    const float* W_ih = (const float*)d_in[1];
    const float* W_hh = (const float*)d_in[2];
    const float* b_ih = (const float*)d_in[3];
    const float* b_hh = (const float*)d_in[4];
    float* out = (float*)d_out;

    char* p = (char*)d_ws;
    float* bg    = (float*)p;   p += 16384;
    u16* Wih     = (u16*)p;     p += (size_t)4096 * 1024 * 2;
    u16* Whh     = (u16*)p;     p += (size_t)4096 * 2048 * 2;
    u16* xb      = (u16*)p;     p += (size_t)4095 * 1024 * 2 + 2048;
    float* gates = (float*)p;   p += (size_t)2048 * 4096 * 4;   // partial slabs (<=32MB)
    u16* hb0     = (u16*)p;     p += (size_t)2048 * 1024 * 2;
    u16* hb1     = (u16*)p;     p += (size_t)2048 * 1024 * 2;
    float* cb0   = (float*)p;   p += (size_t)2048 * 1024 * 4;
    float* cb1   = (float*)p;   p += (size_t)2048 * 1024 * 4;

    bias_kernel<<<16, 256, 0, stream>>>(b_ih, b_hh, bg);
    split_w_hi<10><<<4096, 256, 0, stream>>>(W_ih, Wih);   // 4096*1024/4/256
    split_w_hi<11><<<8192, 256, 0, stream>>>(W_hh, Whh);   // 4096*2048/4/256
    conv_emb<<<4095, 256, 0, stream>>>(emb, xb);

    const u16* hprev = nullptr;
    const float* cprev = nullptr;
    int buf = 0;
    for (int k = TREE_DEPTH - 1; k >= 0; --k) {
        const int n = 1 << k;
        const u16* x = xb + (size_t)(n - 1) * 1024;
        const int has_h = (k != TREE_DEPTH - 1);
        const int Ktot = has_h ? 3072 : 1024;
        u16*   hn = buf ? hb1 : hb0;
        float* cn = buf ? cb1 : cb0;
        float* outp = (k == 0) ? out : nullptr;

        int KS;
        if (n >= 128) {
            // K-split so grid >= 256 blocks
            KS = (k == 11) ? 1 : (k == 10) ? 2 : (k == 9) ? 4 : 8;
            dim3 grid(n / 128, GCOLS / 128, KS);
            gemm_big<<<grid, 256, 0, stream>>>(x, hprev, Wih, Whh, gates,
                                               n, Ktot / KS);
        } else {
            KS = 8;
            dim3 grid((n + 15) / 16, GCOLS / 64, 8);
            gemm_small<<<grid, 256, 0, stream>>>(x, hprev, Wih, Whh, gates, n);
        }
        const int tot = n * 256;
        level_act<<<(tot + 255) / 256, 256, 0, stream>>>(
            gates, KS, (size_t)n * GCOLS, bg, cprev, hn, cn, outp, n, has_h);

        hprev = hn; cprev = cn; buf ^= 1;
    }
}